// Round 2
// baseline (446.764 us; speedup 1.0000x reference)
//
#include <hip/hip_runtime.h>
#include <cstdint>
#include <cstddef>

typedef __attribute__((ext_vector_type(8))) short short8;
typedef __attribute__((ext_vector_type(4))) float f32x4;

#define MFMA16(a,b,c) __builtin_amdgcn_mfma_f32_16x16x32_bf16((a),(b),(c),0,0,0)

static __device__ __forceinline__ float bf2f(unsigned short u){
    unsigned int x = ((unsigned int)u) << 16;
    return __builtin_bit_cast(float, x);
}
static __device__ __forceinline__ unsigned short f2bf(float f){
    unsigned int x = __builtin_bit_cast(unsigned int, f);
    x = x + 0x7FFFu + ((x >> 16) & 1u);
    return (unsigned short)(x >> 16);
}

// ---------------------------------------------------------------------------
// Shapes (fixed): B=8, C=128, H=W=128; mem_c=64, h2=w2=64.
// ---------------------------------------------------------------------------

// K_prep: bf16 weight copies + LN folding vectors.
__global__ void k_prep(const float* __restrict__ Wl1, const float* __restrict__ bl1,
                       const float* __restrict__ Wr1, const float* __restrict__ br1,
                       const float* __restrict__ Wl2, const float* __restrict__ Wr2,
                       const float* __restrict__ Wf,
                       const float* __restrict__ nlw, const float* __restrict__ nlb,
                       const float* __restrict__ nrw, const float* __restrict__ nrb,
                       unsigned short* __restrict__ wl1e, unsigned short* __restrict__ wr1e,
                       unsigned short* __restrict__ wl2b, unsigned short* __restrict__ wr2b,
                       unsigned short* __restrict__ wf1b, unsigned short* __restrict__ wf2b,
                       float* __restrict__ S1l, float* __restrict__ S1r,
                       float* __restrict__ beffl, float* __restrict__ beffr)
{
    int o = blockIdx.x;
    int c = threadIdx.x;  // 128 threads
    float wl = Wl1[o*128+c] * nlw[c];
    unsigned short wlb = f2bf(wl);
    wl1e[o*128+c] = wlb;
    float wr = Wr1[o*128+c] * nrw[c];
    unsigned short wrb = f2bf(wr);
    wr1e[o*128+c] = wrb;
    wl2b[o*128+c] = f2bf(Wl2[o*128+c]);
    wr2b[o*128+c] = f2bf(Wr2[o*128+c]);
    wf1b[o*128+c] = f2bf(Wf[o*256+c]);
    wf2b[o*128+c] = f2bf(Wf[o*256+128+c]);

    __shared__ float red[4][128];
    red[0][c] = bf2f(wlb);
    red[1][c] = Wl1[o*128+c]*nlb[c];
    red[2][c] = bf2f(wrb);
    red[3][c] = Wr1[o*128+c]*nrb[c];
    __syncthreads();
    if (c < 4) {
        float s = 0.f;
        for (int i = 0; i < 128; i++) s += red[c][i];
        if      (c == 0) S1l[o]   = s;
        else if (c == 1) beffl[o] = bl1[o] + s;
        else if (c == 2) S1r[o]   = s;
        else             beffr[o] = br1[o] + s;
    }
}

// K1: mem conv 64->128 channels on 64x64, output NHWC bf16 R0n[b][p][o].
__global__ void k_memconv(const float* __restrict__ xr, const float* __restrict__ Wm,
                          const float* __restrict__ bm, unsigned short* __restrict__ R0n)
{
    __shared__ float Xs[64][65];
    __shared__ float Ws[128][65];
    int blk = blockIdx.x;          // 512 = 8 b * 64 chunks
    int b  = blk >> 6;
    int p0 = (blk & 63) * 64;
    int t = threadIdx.x;           // 256 threads
    for (int k = 0; k < 16; k++) {
        int idx = t + 256*k;       // 4096
        int c = idx >> 6, pi = idx & 63;
        Xs[c][pi] = xr[((long)b*64 + c)*4096 + p0 + pi];
    }
    for (int k = 0; k < 32; k++) {
        int idx = t + 256*k;       // 8192
        int o = idx >> 6, c = idx & 63;
        Ws[o][c] = Wm[o*64 + c];
    }
    __syncthreads();
    int og = t >> 3, pg = t & 7;   // 32 o-groups x 8 p-groups
    int o0 = og*4, pp0 = pg*8;
    float acc[4][8];
    #pragma unroll
    for (int j = 0; j < 4; j++)
        #pragma unroll
        for (int k = 0; k < 8; k++) acc[j][k] = bm[o0+j];
    for (int c = 0; c < 64; c++) {
        float xv[8], wv[4];
        #pragma unroll
        for (int k = 0; k < 8; k++) xv[k] = Xs[c][pp0+k];
        #pragma unroll
        for (int j = 0; j < 4; j++) wv[j] = Ws[o0+j][c];
        #pragma unroll
        for (int j = 0; j < 4; j++)
            #pragma unroll
            for (int k = 0; k < 8; k++) acc[j][k] += wv[j]*xv[k];
    }
    #pragma unroll
    for (int j = 0; j < 4; j++)
        #pragma unroll
        for (int k = 0; k < 8; k++)
            R0n[((long)b*4096 + p0 + pp0 + k)*128 + o0 + j] = f2bf(acc[j][k]);
}

// K2: bilinear upsample (align_corners) 64x64 -> 128x128, NHWC bf16.
__global__ void k_upsample(const unsigned short* __restrict__ R0n,
                           unsigned short* __restrict__ XR)
{
    int t = threadIdx.x;
    int c = t & 127;
    long pix = (long)blockIdx.x * 2 + (t >> 7);   // 0 .. 131071
    int b = (int)(pix >> 14);
    int rem = (int)(pix & 16383);
    int Y = rem >> 7, X = rem & 127;
    const float s = 63.0f / 127.0f;
    float cy = Y * s, cx = X * s;
    int y0 = min((int)floorf(cy), 62);
    int x0 = min((int)floorf(cx), 62);
    float fy = cy - (float)y0, fx = cx - (float)x0;
    const unsigned short* base = R0n + ((long)b*4096)*128;
    float v00 = bf2f(base[(y0*64 + x0    )*128 + c]);
    float v01 = bf2f(base[(y0*64 + x0 + 1)*128 + c]);
    float v10 = bf2f(base[((y0+1)*64 + x0    )*128 + c]);
    float v11 = bf2f(base[((y0+1)*64 + x0 + 1)*128 + c]);
    float r0 = v00*(1.f-fy) + v10*fy;
    float r1 = v01*(1.f-fy) + v11*fy;
    XR[pix*128 + c] = f2bf(r0*(1.f-fx) + r1*fx);
}

// K3: NCHW f32 -> NHWC bf16 transpose of x_l.
__global__ void k_transpose(const float* __restrict__ xl, unsigned short* __restrict__ XL)
{
    __shared__ float tile[32][33];
    int blk = blockIdx.x;          // 16384 = 8 b * 4 ct * 512 pt
    int pt = blk & 511;
    int ct = (blk >> 9) & 3;
    int b  = blk >> 11;
    int p0 = pt*32, c0 = ct*32;
    int t = threadIdx.x;
    const float* src = xl + (long)b*128*16384;
    #pragma unroll
    for (int k = 0; k < 4; k++) {
        int idx = t + 256*k;
        int ci = idx >> 5, pi = idx & 31;
        tile[ci][pi] = src[(long)(c0+ci)*16384 + p0 + pi];
    }
    __syncthreads();
    unsigned short* dst = XL + (long)b*16384*128;
    #pragma unroll
    for (int k = 0; k < 4; k++) {
        int idx = t + 256*k;
        int pi = idx >> 5, ci = idx & 31;
        dst[(long)(p0+pi)*128 + c0 + ci] = f2bf(tile[ci][pi]);
    }
}

// K3b: per-pixel LayerNorm stats over channels (NHWC bf16 input).
__global__ void k_stats(const unsigned short* __restrict__ X,
                        float* __restrict__ mu, float* __restrict__ rs, int npix)
{
    int t = threadIdx.x;
    int lane = t & 63, wv = t >> 6;
    long pix = (long)blockIdx.x*4 + wv;
    if (pix >= npix) return;
    const unsigned short* row = X + pix*128;
    unsigned int pr = *(const unsigned int*)(row + lane*2);
    float a = bf2f((unsigned short)(pr & 0xFFFFu));
    float b = bf2f((unsigned short)(pr >> 16));
    float s = a + b, s2 = a*a + b*b;
    #pragma unroll
    for (int d = 1; d < 64; d <<= 1) { s += __shfl_xor(s, d); s2 += __shfl_xor(s2, d); }
    if (lane == 0) {
        float m = s * (1.0f/128.0f);
        float var = s2 * (1.0f/128.0f) - m*m;
        mu[pix] = m;
        rs[pix] = rsqrtf(var + 1e-6f);
    }
}

// K4: fused per-(b,h) SCAM: 4 convs + bidirectional softmax attention + final conv.
#define LDQ 136
constexpr int K4_LDS = 4*128*LDQ*2 + (13*128 + 8*128 + 256)*4;  // 151040 B

__global__ __launch_bounds__(512) void k_scam(
    const unsigned short* __restrict__ XL, const unsigned short* __restrict__ XR,
    const unsigned short* __restrict__ wl1e, const unsigned short* __restrict__ wr1e,
    const unsigned short* __restrict__ wl2b, const unsigned short* __restrict__ wr2b,
    const unsigned short* __restrict__ wf1b, const unsigned short* __restrict__ wf2b,
    const float* __restrict__ muL, const float* __restrict__ rsL,
    const float* __restrict__ muR, const float* __restrict__ rsR,
    const float* __restrict__ S1l, const float* __restrict__ S1r,
    const float* __restrict__ beffl, const float* __restrict__ beffr,
    const float* __restrict__ bl2, const float* __restrict__ br2,
    const float* __restrict__ beta, const float* __restrict__ gam,
    const float* __restrict__ bfv, float* __restrict__ out)
{
    extern __shared__ char smem[];
    unsigned short* bufA  = (unsigned short*)smem;     // QLt -> P1 -> A1t  [128][LDQ]
    unsigned short* bufB  = bufA  + 128*LDQ;           // QRt -> P2t -> A2t
    unsigned short* bufVL = bufB  + 128*LDQ;           // VL [c][w]
    unsigned short* bufVR = bufVL + 128*LDQ;           // VR [c][v]
    float* vecs    = (float*)(bufVR + 128*LDQ);        // 13 x 128
    float* colpart = vecs + 13*128;                    // 8 x 128
    float* colred  = colpart + 8*128;                  // 2 x 128 (colmax, colsum)

    int tid = threadIdx.x;
    int lane = tid & 63, wv = tid >> 6;    // 8 waves
    int l16 = lane & 15, lg = lane >> 4;
    int bh = blockIdx.x;
    int b = bh >> 7, h = bh & 127;
    long pixbase = (long)b*16384 + (long)h*128;
    const unsigned short* Abl = XL + pixbase*128;
    const unsigned short* Abr = XR + pixbase*128;

    if (tid < 128) {
        vecs[0*128+tid]  = muL[pixbase + tid];
        vecs[1*128+tid]  = rsL[pixbase + tid];
        vecs[2*128+tid]  = muR[pixbase + tid];
        vecs[3*128+tid]  = rsR[pixbase + tid];
        vecs[4*128+tid]  = S1l[tid];
        vecs[5*128+tid]  = beffl[tid];
        vecs[6*128+tid]  = S1r[tid];
        vecs[7*128+tid]  = beffr[tid];
        vecs[8*128+tid]  = bl2[tid];
        vecs[9*128+tid]  = br2[tid];
        vecs[10*128+tid] = beta[tid];
        vecs[11*128+tid] = gam[tid];
        vecs[12*128+tid] = bfv[tid];
    }
    __syncthreads();

    int p0 = wv * 16;

    // ----- conv phase: A-frags from global NHWC, B-frags = weights ---------
    f32x4 acc[8];
    auto conv = [&](const unsigned short* Asrc, const unsigned short* Wsrc){
        #pragma unroll
        for (int t = 0; t < 8; t++) acc[t] = (f32x4){0.f,0.f,0.f,0.f};
        #pragma unroll
        for (int kc = 0; kc < 4; kc++) {
            short8 a = *(const short8*)(Asrc + (p0+l16)*128 + kc*32 + lg*8);
            #pragma unroll
            for (int t = 0; t < 8; t++) {
                short8 bw = *(const short8*)(Wsrc + (t*16+l16)*128 + kc*32 + lg*8);
                acc[t] = MFMA16(a, bw, acc[t]);
            }
        }
    };
    auto epiQ = [&](const float* vmu, const float* vrs, const float* vS1,
                    const float* vbe, unsigned short* dst){
        #pragma unroll
        for (int r = 0; r < 4; r++) {
            int p = p0 + lg*4 + r;
            float mu = vmu[p], rs = vrs[p];
            #pragma unroll
            for (int t = 0; t < 8; t++) {
                int o = t*16 + l16;
                dst[p*LDQ + o] = f2bf(rs*(acc[t][r] - mu*vS1[o]) + vbe[o]);
            }
        }
    };
    auto epiV = [&](const float* vb, unsigned short* dst){
        #pragma unroll
        for (int t = 0; t < 8; t++) {
            int o = t*16 + l16;
            float bias = vb[o];
            #pragma unroll
            for (int r = 0; r < 4; r++) {
                int p = p0 + lg*4 + r;
                dst[o*LDQ + p] = f2bf(acc[t][r] + bias);
            }
        }
    };

    conv(Abl, wl1e); epiQ(vecs+0*128, vecs+1*128, vecs+4*128, vecs+5*128, bufA);
    conv(Abr, wr1e); epiQ(vecs+2*128, vecs+3*128, vecs+6*128, vecs+7*128, bufB);
    conv(Abl, wl2b); epiV(vecs+8*128, bufVL);
    conv(Abr, wr2b); epiV(vecs+9*128, bufVR);
    __syncthreads();

    // ----- S = QLt @ QRt^T * scale -----------------------------------------
    int w0 = p0;
    f32x4 s[8];
    #pragma unroll
    for (int t = 0; t < 8; t++) s[t] = (f32x4){0.f,0.f,0.f,0.f};
    #pragma unroll
    for (int kc = 0; kc < 4; kc++) {
        short8 a = *(const short8*)(bufA + (w0+l16)*LDQ + kc*32 + lg*8);
        #pragma unroll
        for (int t = 0; t < 8; t++) {
            short8 bq = *(const short8*)(bufB + (t*16+l16)*LDQ + kc*32 + lg*8);
            s[t] = MFMA16(a, bq, s[t]);
        }
    }
    const float scale = 0.08838834764831845f;   // 128^-0.5
    #pragma unroll
    for (int t = 0; t < 8; t++)
        #pragma unroll
        for (int r = 0; r < 4; r++) s[t][r] *= scale;

    // row max (full row within wave)
    float rm[4];
    #pragma unroll
    for (int r = 0; r < 4; r++) {
        float m = s[0][r];
        #pragma unroll
        for (int t = 1; t < 8; t++) m = fmaxf(m, s[t][r]);
        #pragma unroll
        for (int d = 1; d < 16; d <<= 1) m = fmaxf(m, __shfl_xor(m, d));
        rm[r] = m;
    }
    // column partial max -> LDS
    #pragma unroll
    for (int t = 0; t < 8; t++) {
        float m = fmaxf(fmaxf(s[t][0], s[t][1]), fmaxf(s[t][2], s[t][3]));
        m = fmaxf(m, __shfl_xor(m, 16));
        m = fmaxf(m, __shfl_xor(m, 32));
        if (lane < 16) colpart[wv*128 + t*16 + lane] = m;
    }
    __syncthreads();
    if (tid < 128) {
        float m = colpart[tid];
        for (int i = 1; i < 8; i++) m = fmaxf(m, colpart[i*128 + tid]);
        colred[tid] = m;
    }
    __syncthreads();

    // e1 = exp(S - rowmax), row sums, write P1 (normalized) into bufA
    float rsum[4];
    #pragma unroll
    for (int r = 0; r < 4; r++) {
        float a = 0.f;
        #pragma unroll
        for (int t = 0; t < 8; t++) { float e = __expf(s[t][r] - rm[r]); s[t][r] = e; a += e; }
        #pragma unroll
        for (int d = 1; d < 16; d <<= 1) a += __shfl_xor(a, d);
        rsum[r] = a;
    }
    #pragma unroll
    for (int t = 0; t < 8; t++) {
        #pragma unroll
        for (int r = 0; r < 4; r++) {
            bufA[(w0 + lg*4 + r)*LDQ + t*16 + l16] = f2bf(s[t][r] / rsum[r]);
        }
    }
    // e2 = e1 * exp(rm - colmax); column partial sums
    #pragma unroll
    for (int t = 0; t < 8; t++) {
        float cmax = colred[t*16 + l16];
        float a = 0.f;
        #pragma unroll
        for (int r = 0; r < 4; r++) {
            float e2 = s[t][r] * __expf(rm[r] - cmax);
            s[t][r] = e2; a += e2;
        }
        a += __shfl_xor(a, 16);
        a += __shfl_xor(a, 32);
        if (lane < 16) colpart[wv*128 + t*16 + lane] = a;
    }
    __syncthreads();
    if (tid < 128) {
        float sm = 0.f;
        for (int i = 0; i < 8; i++) sm += colpart[i*128 + tid];
        colred[128 + tid] = sm;
    }
    __syncthreads();
    // write P2t (softmax over w, transposed [v][w]) into bufB
    #pragma unroll
    for (int t = 0; t < 8; t++) {
        float inv = 1.0f / colred[128 + t*16 + l16];
        #pragma unroll
        for (int r = 0; r < 4; r++) {
            bufB[(t*16 + l16)*LDQ + w0 + lg*4 + r] = f2bf(s[t][r] * inv);
        }
    }
    __syncthreads();

    // ----- PV GEMMs ---------------------------------------------------------
    f32x4 f1[8], f2[8];
    #pragma unroll
    for (int t = 0; t < 8; t++) { f1[t] = (f32x4){0.f,0.f,0.f,0.f}; f2[t] = (f32x4){0.f,0.f,0.f,0.f}; }
    #pragma unroll
    for (int kc = 0; kc < 4; kc++) {
        short8 a1 = *(const short8*)(bufA + (w0+l16)*LDQ + kc*32 + lg*8);  // P1[w][v]
        short8 a2 = *(const short8*)(bufB + (w0+l16)*LDQ + kc*32 + lg*8);  // P2t[v][w]
        #pragma unroll
        for (int t = 0; t < 8; t++) {
            short8 bv1 = *(const short8*)(bufVR + (t*16+l16)*LDQ + kc*32 + lg*8);
            f1[t] = MFMA16(a1, bv1, f1[t]);
            short8 bv2 = *(const short8*)(bufVL + (t*16+l16)*LDQ + kc*32 + lg*8);
            f2[t] = MFMA16(a2, bv2, f2[t]);
        }
    }
    __syncthreads();

    // ----- residual + beta/gamma -> A1t/A2t --------------------------------
    #pragma unroll
    for (int t = 0; t < 8; t++) {
        int c = t*16 + l16;
        float bet = vecs[10*128 + c], gm = vecs[11*128 + c];
        #pragma unroll
        for (int r = 0; r < 4; r++) {
            int p = w0 + lg*4 + r;
            float xl = bf2f(Abl[p*128 + c]);
            bufA[p*LDQ + c] = f2bf(xl + bet*f1[t][r]);
            float xr = bf2f(Abr[p*128 + c]);
            bufB[p*LDQ + c] = f2bf(xr + gm*f2[t][r]);
        }
    }
    __syncthreads();

    // ----- final conv: out[o][w] = Wf1@A1t + Wf2@A2t + bf -------------------
    int o0 = wv * 16;
    f32x4 oacc[8];
    #pragma unroll
    for (int t = 0; t < 8; t++) oacc[t] = (f32x4){0.f,0.f,0.f,0.f};
    #pragma unroll
    for (int kc = 0; kc < 4; kc++) {
        short8 aw1 = *(const short8*)(wf1b + (o0+l16)*128 + kc*32 + lg*8);
        short8 aw2 = *(const short8*)(wf2b + (o0+l16)*128 + kc*32 + lg*8);
        #pragma unroll
        for (int t = 0; t < 8; t++) {
            short8 b1 = *(const short8*)(bufA + (t*16+l16)*LDQ + kc*32 + lg*8);
            oacc[t] = MFMA16(aw1, b1, oacc[t]);
            short8 b2 = *(const short8*)(bufB + (t*16+l16)*LDQ + kc*32 + lg*8);
            oacc[t] = MFMA16(aw2, b2, oacc[t]);
        }
    }
    float* outb = out + (long)b*2097152 + (long)h*128;
    #pragma unroll
    for (int t = 0; t < 8; t++) {
        #pragma unroll
        for (int r = 0; r < 4; r++) {
            int o = o0 + lg*4 + r;
            outb[(long)o*16384 + t*16 + l16] = oacc[t][r] + vecs[12*128 + o];
        }
    }
}

// ---------------------------------------------------------------------------
extern "C" void kernel_launch(void* const* d_in, const int* in_sizes, int n_in,
                              void* d_out, int out_size, void* d_ws, size_t ws_size,
                              hipStream_t stream)
{
    const float* x_l = (const float*)d_in[0];
    const float* x_r = (const float*)d_in[1];
    const float* Wm  = (const float*)d_in[2];
    const float* bm  = (const float*)d_in[3];
    const float* nlw = (const float*)d_in[4];
    const float* nlb = (const float*)d_in[5];
    const float* nrw = (const float*)d_in[6];
    const float* nrb = (const float*)d_in[7];
    const float* Wl1 = (const float*)d_in[8];
    const float* bl1 = (const float*)d_in[9];
    const float* Wr1 = (const float*)d_in[10];
    const float* br1 = (const float*)d_in[11];
    const float* Wl2 = (const float*)d_in[12];
    const float* bl2 = (const float*)d_in[13];
    const float* Wr2 = (const float*)d_in[14];
    const float* br2 = (const float*)d_in[15];
    const float* beta = (const float*)d_in[16];
    const float* gam  = (const float*)d_in[17];
    const float* Wf   = (const float*)d_in[18];
    const float* bf   = (const float*)d_in[19];
    float* out = (float*)d_out;

    char* ws = (char*)d_ws;
    size_t off = 0;
    auto alloc = [&](size_t bytes) -> void* {
        void* p = ws + off;
        off += (bytes + 255) & ~(size_t)255;
        return p;
    };
    unsigned short* XL   = (unsigned short*)alloc((size_t)16777216*2);
    unsigned short* XR   = (unsigned short*)alloc((size_t)16777216*2);
    unsigned short* R0n  = (unsigned short*)alloc((size_t)4194304*2);
    float* muL = (float*)alloc((size_t)131072*4);
    float* rsL = (float*)alloc((size_t)131072*4);
    float* muR = (float*)alloc((size_t)131072*4);
    float* rsR = (float*)alloc((size_t)131072*4);
    unsigned short* wl1e = (unsigned short*)alloc((size_t)16384*2);
    unsigned short* wr1e = (unsigned short*)alloc((size_t)16384*2);
    unsigned short* wl2b = (unsigned short*)alloc((size_t)16384*2);
    unsigned short* wr2b = (unsigned short*)alloc((size_t)16384*2);
    unsigned short* wf1b = (unsigned short*)alloc((size_t)16384*2);
    unsigned short* wf2b = (unsigned short*)alloc((size_t)16384*2);
    float* S1l   = (float*)alloc(128*4);
    float* S1r   = (float*)alloc(128*4);
    float* beffl = (float*)alloc(128*4);
    float* beffr = (float*)alloc(128*4);

    (void)in_sizes; (void)n_in; (void)out_size; (void)ws_size;

    hipFuncSetAttribute((const void*)k_scam,
                        hipFuncAttributeMaxDynamicSharedMemorySize, K4_LDS);

    k_prep<<<128, 128, 0, stream>>>(Wl1, bl1, Wr1, br1, Wl2, Wr2, Wf,
                                    nlw, nlb, nrw, nrb,
                                    wl1e, wr1e, wl2b, wr2b, wf1b, wf2b,
                                    S1l, S1r, beffl, beffr);
    k_memconv<<<512, 256, 0, stream>>>(x_r, Wm, bm, R0n);
    k_upsample<<<65536, 256, 0, stream>>>(R0n, XR);
    k_transpose<<<16384, 256, 0, stream>>>(x_l, XL);
    k_stats<<<32768, 256, 0, stream>>>(XL, muL, rsL, 131072);
    k_stats<<<32768, 256, 0, stream>>>(XR, muR, rsR, 131072);
    k_scam<<<1024, 512, K4_LDS, stream>>>(XL, XR, wl1e, wr1e, wl2b, wr2b,
                                          wf1b, wf2b, muL, rsL, muR, rsR,
                                          S1l, S1r, beffl, beffr,
                                          bl2, br2, beta, gam, bf, out);
}

// Round 4
// 419.751 us; speedup vs baseline: 1.0644x; 1.0644x over previous
//
#include <hip/hip_runtime.h>
#include <cstdint>
#include <cstddef>

typedef __attribute__((ext_vector_type(8))) short short8;
typedef __attribute__((ext_vector_type(4))) float f32x4;

#define MFMA16(a,b,c) __builtin_amdgcn_mfma_f32_16x16x32_bf16((a),(b),(c),0,0,0)

static __device__ __forceinline__ float bf2f(unsigned short u){
    unsigned int x = ((unsigned int)u) << 16;
    return __builtin_bit_cast(float, x);
}
static __device__ __forceinline__ unsigned short f2bf(float f){
    unsigned int x = __builtin_bit_cast(unsigned int, f);
    x = x + 0x7FFFu + ((x >> 16) & 1u);
    return (unsigned short)(x >> 16);
}

// ---------------------------------------------------------------------------
// Shapes (fixed): B=8, C=128, H=W=128; mem_c=64, h2=w2=64.
// ---------------------------------------------------------------------------

// K_prep: bf16 weight copies + LN folding vectors.
__global__ void k_prep(const float* __restrict__ Wl1, const float* __restrict__ bl1,
                       const float* __restrict__ Wr1, const float* __restrict__ br1,
                       const float* __restrict__ Wl2, const float* __restrict__ Wr2,
                       const float* __restrict__ Wf,
                       const float* __restrict__ nlw, const float* __restrict__ nlb,
                       const float* __restrict__ nrw, const float* __restrict__ nrb,
                       unsigned short* __restrict__ wl1e, unsigned short* __restrict__ wr1e,
                       unsigned short* __restrict__ wl2b, unsigned short* __restrict__ wr2b,
                       unsigned short* __restrict__ wf1b, unsigned short* __restrict__ wf2b,
                       float* __restrict__ S1l, float* __restrict__ S1r,
                       float* __restrict__ beffl, float* __restrict__ beffr)
{
    int o = blockIdx.x;
    int c = threadIdx.x;  // 128 threads
    float wl = Wl1[o*128+c] * nlw[c];
    unsigned short wlb = f2bf(wl);
    wl1e[o*128+c] = wlb;
    float wr = Wr1[o*128+c] * nrw[c];
    unsigned short wrb = f2bf(wr);
    wr1e[o*128+c] = wrb;
    wl2b[o*128+c] = f2bf(Wl2[o*128+c]);
    wr2b[o*128+c] = f2bf(Wr2[o*128+c]);
    wf1b[o*128+c] = f2bf(Wf[o*256+c]);
    wf2b[o*128+c] = f2bf(Wf[o*256+128+c]);

    __shared__ float red[4][128];
    red[0][c] = bf2f(wlb);
    red[1][c] = Wl1[o*128+c]*nlb[c];
    red[2][c] = bf2f(wrb);
    red[3][c] = Wr1[o*128+c]*nrb[c];
    __syncthreads();
    int g = c >> 5, j = c & 31;
    float sv = red[g][j] + red[g][j+32] + red[g][j+64] + red[g][j+96];
    #pragma unroll
    for (int d = 1; d < 32; d <<= 1) sv += __shfl_xor(sv, d);
    if (j == 0) {
        if      (g == 0) S1l[o]   = sv;
        else if (g == 1) beffl[o] = bl1[o] + sv;
        else if (g == 2) S1r[o]   = sv;
        else             beffr[o] = br1[o] + sv;
    }
}

// K1: mem conv 64->128 channels on 64x64, output NHWC bf16 R0n[b][p][o].
__global__ void k_memconv(const float* __restrict__ xr, const float* __restrict__ Wm,
                          const float* __restrict__ bm, unsigned short* __restrict__ R0n)
{
    __shared__ float Xs[64][65];
    __shared__ float Ws[128][65];
    int blk = blockIdx.x;          // 512 = 8 b * 64 chunks
    int b  = blk >> 6;
    int p0 = (blk & 63) * 64;
    int t = threadIdx.x;           // 256 threads
    for (int k = 0; k < 16; k++) {
        int idx = t + 256*k;       // 4096
        int c = idx >> 6, pi = idx & 63;
        Xs[c][pi] = xr[((long)b*64 + c)*4096 + p0 + pi];
    }
    for (int k = 0; k < 32; k++) {
        int idx = t + 256*k;       // 8192
        int o = idx >> 6, c = idx & 63;
        Ws[o][c] = Wm[o*64 + c];
    }
    __syncthreads();
    int og = t >> 3, pg = t & 7;   // 32 o-groups x 8 p-groups
    int o0 = og*4, pp0 = pg*8;
    float acc[4][8];
    #pragma unroll
    for (int j = 0; j < 4; j++)
        #pragma unroll
        for (int k = 0; k < 8; k++) acc[j][k] = bm[o0+j];
    for (int c = 0; c < 64; c++) {
        float xv[8], wv[4];
        #pragma unroll
        for (int k = 0; k < 8; k++) xv[k] = Xs[c][pp0+k];
        #pragma unroll
        for (int j = 0; j < 4; j++) wv[j] = Ws[o0+j][c];
        #pragma unroll
        for (int j = 0; j < 4; j++)
            #pragma unroll
            for (int k = 0; k < 8; k++) acc[j][k] += wv[j]*xv[k];
    }
    #pragma unroll
    for (int j = 0; j < 4; j++)
        #pragma unroll
        for (int k = 0; k < 8; k++)
            R0n[((long)b*4096 + p0 + pp0 + k)*128 + o0 + j] = f2bf(acc[j][k]);
}

// K2: bilinear upsample (align_corners) 64x64 -> 128x128 NHWC bf16 + LN stats.
__global__ void k_xr(const unsigned short* __restrict__ R0n,
                     unsigned short* __restrict__ XR,
                     float* __restrict__ muR, float* __restrict__ rsR)
{
    __shared__ float part[2][2][2];
    int t = threadIdx.x;
    int c = t & 127;
    int pl = t >> 7;
    long pix = (long)blockIdx.x * 2 + pl;   // 0 .. 131071
    int b = (int)(pix >> 14);
    int rem = (int)(pix & 16383);
    int Y = rem >> 7, X = rem & 127;
    const float sc = 63.0f / 127.0f;
    float cy = Y * sc, cx = X * sc;
    int y0 = min((int)floorf(cy), 62);
    int x0 = min((int)floorf(cx), 62);
    float fy = cy - (float)y0, fx = cx - (float)x0;
    const unsigned short* base = R0n + ((long)b*4096)*128;
    float v00 = bf2f(base[(y0*64 + x0    )*128 + c]);
    float v01 = bf2f(base[(y0*64 + x0 + 1)*128 + c]);
    float v10 = bf2f(base[((y0+1)*64 + x0    )*128 + c]);
    float v11 = bf2f(base[((y0+1)*64 + x0 + 1)*128 + c]);
    float r0 = v00*(1.f-fy) + v10*fy;
    float r1 = v01*(1.f-fy) + v11*fy;
    float val = r0*(1.f-fx) + r1*fx;
    XR[pix*128 + c] = f2bf(val);
    float sv = val, s2 = val*val;
    #pragma unroll
    for (int d = 1; d < 64; d <<= 1) { sv += __shfl_xor(sv, d); s2 += __shfl_xor(s2, d); }
    int wh = (t >> 6) & 1;
    if ((t & 63) == 0) { part[pl][wh][0] = sv; part[pl][wh][1] = s2; }
    __syncthreads();
    if ((t & 127) == 0) {
        float S  = part[pl][0][0] + part[pl][1][0];
        float S2 = part[pl][0][1] + part[pl][1][1];
        float m = S * (1.0f/128.0f);
        float var = S2 * (1.0f/128.0f) - m*m;
        muR[pix] = m;
        rsR[pix] = rsqrtf(var + 1e-6f);
    }
}

// K3: NCHW f32 -> NHWC bf16 transpose of x_l + LN stats (fused).
__global__ void k_xl(const float* __restrict__ xl, unsigned short* __restrict__ XL,
                     float* __restrict__ muL, float* __restrict__ rsL)
{
    __shared__ float tile[128][33];
    __shared__ float partS[8][32];
    __shared__ float partS2[8][32];
    int blk = blockIdx.x;           // 4096 = 8 b * 512 chunks of 32 pixels
    int b  = blk >> 9;
    int p0 = (blk & 511) * 32;
    const float* src = xl + (long)b*128*16384;
    int t = threadIdx.x;            // 256
    #pragma unroll
    for (int k = 0; k < 16; k++) {
        int idx = t + 256*k;        // 4096
        int cc = idx >> 5, pi = idx & 31;
        tile[cc][pi] = src[(long)cc*16384 + p0 + pi];
    }
    __syncthreads();
    unsigned short* dst = XL + ((long)b*16384 + p0)*128;
    int cw = t & 127, ph = t >> 7;
    #pragma unroll
    for (int k = 0; k < 16; k++) {
        int pi = ph*16 + k;
        dst[(long)pi*128 + cw] = f2bf(tile[cw][pi]);
    }
    int sub = t >> 5, pj = t & 31;
    float sv = 0.f, s2 = 0.f;
    #pragma unroll
    for (int j = 0; j < 16; j++) { float v = tile[sub*16+j][pj]; sv += v; s2 += v*v; }
    partS[sub][pj] = sv; partS2[sub][pj] = s2;
    __syncthreads();
    if (t < 32) {
        float S = 0.f, S2 = 0.f;
        #pragma unroll
        for (int i = 0; i < 8; i++) { S += partS[i][t]; S2 += partS2[i][t]; }
        float m = S*(1.0f/128.0f), var = S2*(1.0f/128.0f) - m*m;
        muL[(long)b*16384 + p0 + t] = m;
        rsL[(long)b*16384 + p0 + t] = rsqrtf(var + 1e-6f);
    }
}

// K4: fused per-(b,h) SCAM. 16 waves: wave = (rw = row group 0..7, half = col half).
#define LDQ 136
constexpr int K4_LDS = 4*128*LDQ*2 + (13*128 + 8*128 + 8*128 + 2*128 + 2*128)*4; // 156160

__global__ __launch_bounds__(1024) void k_scam(
    const unsigned short* __restrict__ XL, const unsigned short* __restrict__ XR,
    const unsigned short* __restrict__ wl1e, const unsigned short* __restrict__ wr1e,
    const unsigned short* __restrict__ wl2b, const unsigned short* __restrict__ wr2b,
    const unsigned short* __restrict__ wf1b, const unsigned short* __restrict__ wf2b,
    const float* __restrict__ muL, const float* __restrict__ rsL,
    const float* __restrict__ muR, const float* __restrict__ rsR,
    const float* __restrict__ S1l, const float* __restrict__ S1r,
    const float* __restrict__ beffl, const float* __restrict__ beffr,
    const float* __restrict__ bl2, const float* __restrict__ br2,
    const float* __restrict__ beta, const float* __restrict__ gam,
    const float* __restrict__ bfv, float* __restrict__ out)
{
    extern __shared__ char smem[];
    unsigned short* bufA  = (unsigned short*)smem;     // QLt -> P1 -> A1t  [128][LDQ]
    unsigned short* bufB  = bufA  + 128*LDQ;           // QRt -> P2t -> A2t
    unsigned short* bufVL = bufB  + 128*LDQ;           // VL [c][w] -> xl stage [p][c]
    unsigned short* bufVR = bufVL + 128*LDQ;           // VR [c][v] -> xr stage [p][c]
    float* vecs     = (float*)(bufVR + 128*LDQ);       // 13 x 128
    float* colpart  = vecs + 13*128;                   // 8 x 128  (col max partials)
    float* colpart2 = colpart + 8*128;                 // 8 x 128  (col sum partials)
    float* rowmax   = colpart2 + 8*128;                // 2 x 128
    float* rowsum   = rowmax + 2*128;                  // 2 x 128

    int tid = threadIdx.x;
    int lane = tid & 63, wv = tid >> 6;    // 16 waves
    int l16 = lane & 15, lg = lane >> 4;
    int rw = wv & 7, half = wv >> 3;
    int p0 = rw * 16;                       // row base (pixels / S rows / out-chan base)
    int th = half * 4;                      // t-tile base: tiles th..th+3 (64 cols)
    int bh = blockIdx.x;
    int b = bh >> 7, h = bh & 127;
    long pixbase = (long)b*16384 + (long)h*128;
    const unsigned short* Abl = XL + pixbase*128;
    const unsigned short* Abr = XR + pixbase*128;

    if (tid < 128) {
        vecs[0*128+tid]  = muL[pixbase + tid];
        vecs[1*128+tid]  = rsL[pixbase + tid];
        vecs[2*128+tid]  = muR[pixbase + tid];
        vecs[3*128+tid]  = rsR[pixbase + tid];
        vecs[4*128+tid]  = S1l[tid];
        vecs[5*128+tid]  = beffl[tid];
        vecs[6*128+tid]  = S1r[tid];
        vecs[7*128+tid]  = beffr[tid];
        vecs[8*128+tid]  = bl2[tid];
        vecs[9*128+tid]  = br2[tid];
        vecs[10*128+tid] = beta[tid];
        vecs[11*128+tid] = gam[tid];
        vecs[12*128+tid] = bfv[tid];
    }
    __syncthreads();                                   // B1

    // ----- conv phase ------------------------------------------------------
    f32x4 acc[4];
    auto conv = [&](const unsigned short* Asrc, const unsigned short* Wsrc){
        #pragma unroll
        for (int t4 = 0; t4 < 4; t4++) acc[t4] = (f32x4){0.f,0.f,0.f,0.f};
        #pragma unroll
        for (int kc = 0; kc < 4; kc++) {
            short8 a = *(const short8*)(Asrc + (p0+l16)*128 + kc*32 + lg*8);
            #pragma unroll
            for (int t4 = 0; t4 < 4; t4++) {
                int tt = th + t4;
                short8 bw = *(const short8*)(Wsrc + (tt*16+l16)*128 + kc*32 + lg*8);
                acc[t4] = MFMA16(a, bw, acc[t4]);
            }
        }
    };
    auto epiQ = [&](const float* vmu, const float* vrs, const float* vS1,
                    const float* vbe, unsigned short* dstb){
        #pragma unroll
        for (int r = 0; r < 4; r++) {
            int p = p0 + lg*4 + r;
            float mu = vmu[p], rs = vrs[p];
            #pragma unroll
            for (int t4 = 0; t4 < 4; t4++) {
                int o = (th+t4)*16 + l16;
                dstb[p*LDQ + o] = f2bf(rs*(acc[t4][r] - mu*vS1[o]) + vbe[o]);
            }
        }
    };
    auto epiV = [&](const float* vb, unsigned short* dstb){
        #pragma unroll
        for (int t4 = 0; t4 < 4; t4++) {
            int o = (th+t4)*16 + l16;
            float bias = vb[o];
            #pragma unroll
            for (int r = 0; r < 4; r++) {
                int p = p0 + lg*4 + r;
                dstb[o*LDQ + p] = f2bf(acc[t4][r] + bias);
            }
        }
    };

    conv(Abl, wl1e); epiQ(vecs+0*128, vecs+1*128, vecs+4*128, vecs+5*128, bufA);
    conv(Abr, wr1e); epiQ(vecs+2*128, vecs+3*128, vecs+6*128, vecs+7*128, bufB);
    conv(Abl, wl2b); epiV(vecs+8*128, bufVL);
    conv(Abr, wr2b); epiV(vecs+9*128, bufVR);
    __syncthreads();                                   // B2

    // ----- S = QLt @ QRt^T * scale  (wave: rows p0.., cols th-tiles) -------
    f32x4 s[4];
    #pragma unroll
    for (int t4 = 0; t4 < 4; t4++) s[t4] = (f32x4){0.f,0.f,0.f,0.f};
    #pragma unroll
    for (int kc = 0; kc < 4; kc++) {
        short8 a = *(const short8*)(bufA + (p0+l16)*LDQ + kc*32 + lg*8);
        #pragma unroll
        for (int t4 = 0; t4 < 4; t4++) {
            short8 bq = *(const short8*)(bufB + ((th+t4)*16+l16)*LDQ + kc*32 + lg*8);
            s[t4] = MFMA16(a, bq, s[t4]);
        }
    }
    const float scale = 0.08838834764831845f;   // 128^-0.5
    #pragma unroll
    for (int t4 = 0; t4 < 4; t4++)
        #pragma unroll
        for (int r = 0; r < 4; r++) s[t4][r] *= scale;

    // partial row max (this wave's 64 cols)
    float rm[4];
    #pragma unroll
    for (int r = 0; r < 4; r++) {
        float m = fmaxf(fmaxf(s[0][r], s[1][r]), fmaxf(s[2][r], s[3][r]));
        #pragma unroll
        for (int d = 1; d < 16; d <<= 1) m = fmaxf(m, __shfl_xor(m, d));
        rm[r] = m;
    }
    if (l16 == 0) {
        #pragma unroll
        for (int r = 0; r < 4; r++) rowmax[half*128 + p0 + lg*4 + r] = rm[r];
    }
    // partial col max (this wave's 16 rows)
    #pragma unroll
    for (int t4 = 0; t4 < 4; t4++) {
        float m = fmaxf(fmaxf(s[t4][0], s[t4][1]), fmaxf(s[t4][2], s[t4][3]));
        m = fmaxf(m, __shfl_xor(m, 16));
        m = fmaxf(m, __shfl_xor(m, 32));
        if (lane < 16) colpart[rw*128 + (th+t4)*16 + lane] = m;
    }
    __syncthreads();                                   // B3

    // combine row max (2 halves) and col max (8 row groups)
    #pragma unroll
    for (int r = 0; r < 4; r++) {
        int row = p0 + lg*4 + r;
        rm[r] = fmaxf(rowmax[row], rowmax[128 + row]);
    }
    float cmax[4];
    #pragma unroll
    for (int t4 = 0; t4 < 4; t4++) {
        int col = (th+t4)*16 + l16;
        float m = colpart[col];
        #pragma unroll
        for (int i = 1; i < 8; i++) m = fmaxf(m, colpart[i*128 + col]);
        cmax[t4] = m;
    }

    // e1 = exp(S - rowmax); partial row sums; partial col sums of e2
    float rsumP[4] = {0.f,0.f,0.f,0.f};
    #pragma unroll
    for (int t4 = 0; t4 < 4; t4++)
        #pragma unroll
        for (int r = 0; r < 4; r++) {
            float e = __expf(s[t4][r] - rm[r]);
            s[t4][r] = e; rsumP[r] += e;
        }
    #pragma unroll
    for (int r = 0; r < 4; r++) {
        float a = rsumP[r];
        #pragma unroll
        for (int d = 1; d < 16; d <<= 1) a += __shfl_xor(a, d);
        rsumP[r] = a;
    }
    if (l16 == 0) {
        #pragma unroll
        for (int r = 0; r < 4; r++) rowsum[half*128 + p0 + lg*4 + r] = rsumP[r];
    }
    #pragma unroll
    for (int t4 = 0; t4 < 4; t4++) {
        float a = 0.f;
        #pragma unroll
        for (int r = 0; r < 4; r++) a += s[t4][r] * __expf(rm[r] - cmax[t4]);
        a += __shfl_xor(a, 16);
        a += __shfl_xor(a, 32);
        if (lane < 16) colpart2[rw*128 + (th+t4)*16 + lane] = a;
    }
    __syncthreads();                                   // B4

    // finalize row sums -> write P1 (normalized) into bufA
    float rsum[4];
    #pragma unroll
    for (int r = 0; r < 4; r++) {
        int row = p0 + lg*4 + r;
        rsum[r] = rowsum[row] + rowsum[128 + row];
    }
    #pragma unroll
    for (int t4 = 0; t4 < 4; t4++)
        #pragma unroll
        for (int r = 0; r < 4; r++)
            bufA[(p0 + lg*4 + r)*LDQ + (th+t4)*16 + l16] = f2bf(s[t4][r] / rsum[r]);

    // convert s -> e2; finalize col sums -> write P2t into bufB
    #pragma unroll
    for (int t4 = 0; t4 < 4; t4++) {
        #pragma unroll
        for (int r = 0; r < 4; r++) s[t4][r] *= __expf(rm[r] - cmax[t4]);
        int col = (th+t4)*16 + l16;
        float cs = 0.f;
        #pragma unroll
        for (int i = 0; i < 8; i++) cs += colpart2[i*128 + col];
        float inv = 1.0f / cs;
        #pragma unroll
        for (int r = 0; r < 4; r++)
            bufB[col*LDQ + p0 + lg*4 + r] = f2bf(s[t4][r] * inv);
    }
    __syncthreads();                                   // B5

    // ----- PV GEMMs (full 128 contraction; wave: 16 rows x 64 cols) --------
    f32x4 f1[4], f2[4];
    #pragma unroll
    for (int t4 = 0; t4 < 4; t4++) { f1[t4] = (f32x4){0.f,0.f,0.f,0.f}; f2[t4] = (f32x4){0.f,0.f,0.f,0.f}; }
    #pragma unroll
    for (int kc = 0; kc < 4; kc++) {
        short8 a1 = *(const short8*)(bufA + (p0+l16)*LDQ + kc*32 + lg*8);  // P1[w][v]
        short8 a2 = *(const short8*)(bufB + (p0+l16)*LDQ + kc*32 + lg*8);  // P2t[v][w]
        #pragma unroll
        for (int t4 = 0; t4 < 4; t4++) {
            short8 bv1 = *(const short8*)(bufVR + ((th+t4)*16+l16)*LDQ + kc*32 + lg*8);
            f1[t4] = MFMA16(a1, bv1, f1[t4]);
            short8 bv2 = *(const short8*)(bufVL + ((th+t4)*16+l16)*LDQ + kc*32 + lg*8);
            f2[t4] = MFMA16(a2, bv2, f2[t4]);
        }
    }
    __syncthreads();                                   // B6 (bufVL/VR now free)

    // ----- stage xl/xr rows into bufVL/bufVR as [p][c] (coalesced) ---------
    #pragma unroll
    for (int k = 0; k < 2; k++) {
        int idx = tid + 1024*k;          // 2048 groups of 8 shorts
        int p = idx >> 4, cg = idx & 15;
        *(short8*)(bufVL + p*LDQ + cg*8) = *(const short8*)(Abl + p*128 + cg*8);
        *(short8*)(bufVR + p*LDQ + cg*8) = *(const short8*)(Abr + p*128 + cg*8);
    }
    __syncthreads();                                   // B7

    // ----- residual + beta/gamma -> A1t/A2t [p][c] -------------------------
    #pragma unroll
    for (int t4 = 0; t4 < 4; t4++) {
        int c = (th+t4)*16 + l16;
        float bet = vecs[10*128 + c], gm = vecs[11*128 + c];
        #pragma unroll
        for (int r = 0; r < 4; r++) {
            int p = p0 + lg*4 + r;
            float xlv = bf2f(bufVL[p*LDQ + c]);
            bufA[p*LDQ + c] = f2bf(xlv + bet*f1[t4][r]);
            float xrv = bf2f(bufVR[p*LDQ + c]);
            bufB[p*LDQ + c] = f2bf(xrv + gm*f2[t4][r]);
        }
    }
    __syncthreads();                                   // B8

    // ----- final conv: out[o][w] (wave: o in p0.., w in th-tiles) ----------
    f32x4 oacc[4];
    #pragma unroll
    for (int t4 = 0; t4 < 4; t4++) oacc[t4] = (f32x4){0.f,0.f,0.f,0.f};
    #pragma unroll
    for (int kc = 0; kc < 4; kc++) {
        short8 aw1 = *(const short8*)(wf1b + (p0+l16)*128 + kc*32 + lg*8);
        short8 aw2 = *(const short8*)(wf2b + (p0+l16)*128 + kc*32 + lg*8);
        #pragma unroll
        for (int t4 = 0; t4 < 4; t4++) {
            short8 b1 = *(const short8*)(bufA + ((th+t4)*16+l16)*LDQ + kc*32 + lg*8);
            oacc[t4] = MFMA16(aw1, b1, oacc[t4]);
            short8 b2 = *(const short8*)(bufB + ((th+t4)*16+l16)*LDQ + kc*32 + lg*8);
            oacc[t4] = MFMA16(aw2, b2, oacc[t4]);
        }
    }
    float* outb = out + (long)b*2097152 + (long)h*128;
    #pragma unroll
    for (int t4 = 0; t4 < 4; t4++) {
        #pragma unroll
        for (int r = 0; r < 4; r++) {
            int o = p0 + lg*4 + r;
            outb[(long)o*16384 + (th+t4)*16 + l16] = oacc[t4][r] + vecs[12*128 + o];
        }
    }
}

// ---------------------------------------------------------------------------
extern "C" void kernel_launch(void* const* d_in, const int* in_sizes, int n_in,
                              void* d_out, int out_size, void* d_ws, size_t ws_size,
                              hipStream_t stream)
{
    const float* x_l = (const float*)d_in[0];
    const float* x_r = (const float*)d_in[1];
    const float* Wm  = (const float*)d_in[2];
    const float* bm  = (const float*)d_in[3];
    const float* nlw = (const float*)d_in[4];
    const float* nlb = (const float*)d_in[5];
    const float* nrw = (const float*)d_in[6];
    const float* nrb = (const float*)d_in[7];
    const float* Wl1 = (const float*)d_in[8];
    const float* bl1 = (const float*)d_in[9];
    const float* Wr1 = (const float*)d_in[10];
    const float* br1 = (const float*)d_in[11];
    const float* Wl2 = (const float*)d_in[12];
    const float* bl2 = (const float*)d_in[13];
    const float* Wr2 = (const float*)d_in[14];
    const float* br2 = (const float*)d_in[15];
    const float* beta = (const float*)d_in[16];
    const float* gam  = (const float*)d_in[17];
    const float* Wf   = (const float*)d_in[18];
    const float* bf   = (const float*)d_in[19];
    float* out = (float*)d_out;

    char* ws = (char*)d_ws;
    size_t off = 0;
    auto alloc = [&](size_t bytes) -> void* {
        void* p = ws + off;
        off += (bytes + 255) & ~(size_t)255;
        return p;
    };
    unsigned short* XL   = (unsigned short*)alloc((size_t)16777216*2);
    unsigned short* XR   = (unsigned short*)alloc((size_t)16777216*2);
    unsigned short* R0n  = (unsigned short*)alloc((size_t)4194304*2);
    float* muL = (float*)alloc((size_t)131072*4);
    float* rsL = (float*)alloc((size_t)131072*4);
    float* muR = (float*)alloc((size_t)131072*4);
    float* rsR = (float*)alloc((size_t)131072*4);
    unsigned short* wl1e = (unsigned short*)alloc((size_t)16384*2);
    unsigned short* wr1e = (unsigned short*)alloc((size_t)16384*2);
    unsigned short* wl2b = (unsigned short*)alloc((size_t)16384*2);
    unsigned short* wr2b = (unsigned short*)alloc((size_t)16384*2);
    unsigned short* wf1b = (unsigned short*)alloc((size_t)16384*2);
    unsigned short* wf2b = (unsigned short*)alloc((size_t)16384*2);
    float* S1l   = (float*)alloc(128*4);
    float* S1r   = (float*)alloc(128*4);
    float* beffl = (float*)alloc(128*4);
    float* beffr = (float*)alloc(128*4);

    (void)in_sizes; (void)n_in; (void)out_size; (void)ws_size;

    hipFuncSetAttribute((const void*)k_scam,
                        hipFuncAttributeMaxDynamicSharedMemorySize, K4_LDS);

    k_prep<<<128, 128, 0, stream>>>(Wl1, bl1, Wr1, br1, Wl2, Wr2, Wf,
                                    nlw, nlb, nrw, nrb,
                                    wl1e, wr1e, wl2b, wr2b, wf1b, wf2b,
                                    S1l, S1r, beffl, beffr);
    k_memconv<<<512, 256, 0, stream>>>(x_r, Wm, bm, R0n);
    k_xr<<<65536, 256, 0, stream>>>(R0n, XR, muR, rsR);
    k_xl<<<4096, 256, 0, stream>>>(x_l, XL, muL, rsL);
    k_scam<<<1024, 1024, K4_LDS, stream>>>(XL, XR, wl1e, wr1e, wl2b, wr2b,
                                           wf1b, wf2b, muL, rsL, muR, rsR,
                                           S1l, S1r, beffl, beffr,
                                           bl2, br2, beta, gam, bf, out);
}

// Round 5
// 384.041 us; speedup vs baseline: 1.1633x; 1.0930x over previous
//
#include <hip/hip_runtime.h>
#include <cstdint>
#include <cstddef>

typedef __attribute__((ext_vector_type(8))) short short8;
typedef __attribute__((ext_vector_type(4))) float f32x4;
typedef __attribute__((ext_vector_type(4))) float float4v;

#define MFMA16(a,b,c) __builtin_amdgcn_mfma_f32_16x16x32_bf16((a),(b),(c),0,0,0)

static __device__ __forceinline__ float bf2f(unsigned short u){
    unsigned int x = ((unsigned int)u) << 16;
    return __builtin_bit_cast(float, x);
}
static __device__ __forceinline__ unsigned short f2bf(float f){
    unsigned int x = __builtin_bit_cast(unsigned int, f);
    x = x + 0x7FFFu + ((x >> 16) & 1u);
    return (unsigned short)(x >> 16);
}

// ---------------------------------------------------------------------------
// Shapes (fixed): B=8, C=128, H=W=128; mem_c=64, h2=w2=64.
// ---------------------------------------------------------------------------

// K_prep: bf16 weight copies + LN folding vectors.
__global__ void k_prep(const float* __restrict__ Wl1, const float* __restrict__ bl1,
                       const float* __restrict__ Wr1, const float* __restrict__ br1,
                       const float* __restrict__ Wl2, const float* __restrict__ Wr2,
                       const float* __restrict__ Wf,
                       const float* __restrict__ nlw, const float* __restrict__ nlb,
                       const float* __restrict__ nrw, const float* __restrict__ nrb,
                       unsigned short* __restrict__ wl1e, unsigned short* __restrict__ wr1e,
                       unsigned short* __restrict__ wl2b, unsigned short* __restrict__ wr2b,
                       unsigned short* __restrict__ wf1b, unsigned short* __restrict__ wf2b,
                       float* __restrict__ S1l, float* __restrict__ S1r,
                       float* __restrict__ beffl, float* __restrict__ beffr)
{
    int o = blockIdx.x;
    int c = threadIdx.x;  // 128 threads
    float wl = Wl1[o*128+c] * nlw[c];
    unsigned short wlb = f2bf(wl);
    wl1e[o*128+c] = wlb;
    float wr = Wr1[o*128+c] * nrw[c];
    unsigned short wrb = f2bf(wr);
    wr1e[o*128+c] = wrb;
    wl2b[o*128+c] = f2bf(Wl2[o*128+c]);
    wr2b[o*128+c] = f2bf(Wr2[o*128+c]);
    wf1b[o*128+c] = f2bf(Wf[o*256+c]);
    wf2b[o*128+c] = f2bf(Wf[o*256+128+c]);

    __shared__ float red[4][128];
    red[0][c] = bf2f(wlb);
    red[1][c] = Wl1[o*128+c]*nlb[c];
    red[2][c] = bf2f(wrb);
    red[3][c] = Wr1[o*128+c]*nrb[c];
    __syncthreads();
    int g = c >> 5, j = c & 31;
    float sv = red[g][j] + red[g][j+32] + red[g][j+64] + red[g][j+96];
    #pragma unroll
    for (int d = 1; d < 32; d <<= 1) sv += __shfl_xor(sv, d);
    if (j == 0) {
        if      (g == 0) S1l[o]   = sv;
        else if (g == 1) beffl[o] = bl1[o] + sv;
        else if (g == 2) S1r[o]   = sv;
        else             beffr[o] = br1[o] + sv;
    }
}

// K1: mem conv 64->128 channels on 64x64, output NHWC bf16 R0n[b][p][o].
__global__ void k_memconv(const float* __restrict__ xr, const float* __restrict__ Wm,
                          const float* __restrict__ bm, unsigned short* __restrict__ R0n)
{
    __shared__ float Xs[64][65];
    __shared__ float Ws[128][65];
    int blk = blockIdx.x;          // 512 = 8 b * 64 chunks
    int b  = blk >> 6;
    int p0 = (blk & 63) * 64;
    int t = threadIdx.x;           // 256 threads
    for (int k = 0; k < 16; k++) {
        int idx = t + 256*k;       // 4096
        int c = idx >> 6, pi = idx & 63;
        Xs[c][pi] = xr[((long)b*64 + c)*4096 + p0 + pi];
    }
    for (int k = 0; k < 32; k++) {
        int idx = t + 256*k;       // 8192
        int o = idx >> 6, c = idx & 63;
        Ws[o][c] = Wm[o*64 + c];
    }
    __syncthreads();
    int og = t >> 3, pg = t & 7;   // 32 o-groups x 8 p-groups
    int o0 = og*4, pp0 = pg*8;
    float acc[4][8];
    #pragma unroll
    for (int j = 0; j < 4; j++)
        #pragma unroll
        for (int k = 0; k < 8; k++) acc[j][k] = bm[o0+j];
    for (int c = 0; c < 64; c++) {
        float xv[8], wv[4];
        #pragma unroll
        for (int k = 0; k < 8; k++) xv[k] = Xs[c][pp0+k];
        #pragma unroll
        for (int j = 0; j < 4; j++) wv[j] = Ws[o0+j][c];
        #pragma unroll
        for (int j = 0; j < 4; j++)
            #pragma unroll
            for (int k = 0; k < 8; k++) acc[j][k] += wv[j]*xv[k];
    }
    #pragma unroll
    for (int j = 0; j < 4; j++)
        #pragma unroll
        for (int k = 0; k < 8; k++)
            R0n[((long)b*4096 + p0 + pp0 + k)*128 + o0 + j] = f2bf(acc[j][k]);
}

// K2: bilinear upsample + LN stats. 16 threads/pixel x 8 chans, short8 loads.
__global__ void k_xr(const unsigned short* __restrict__ R0n,
                     unsigned short* __restrict__ XR,
                     float* __restrict__ muR, float* __restrict__ rsR)
{
    int t = threadIdx.x;             // 256
    int pl = t >> 4;                 // local pixel 0..15
    int cg = (t & 15) * 8;           // channel group base
    long pix = (long)blockIdx.x * 16 + pl;   // grid 8192
    int b = (int)(pix >> 14);
    int rem = (int)(pix & 16383);
    int Y = rem >> 7, X = rem & 127;
    const float sc = 63.0f / 127.0f;
    float cy = Y * sc, cx = X * sc;
    int y0 = min((int)floorf(cy), 62);
    int x0 = min((int)floorf(cx), 62);
    float fy = cy - (float)y0, fx = cx - (float)x0;
    float w00 = (1.f-fy)*(1.f-fx), w01 = (1.f-fy)*fx, w10 = fy*(1.f-fx), w11 = fy*fx;
    const unsigned short* base = R0n + ((long)b*4096)*128;
    short8 v00 = *(const short8*)(base + (y0*64 + x0    )*128 + cg);
    short8 v01 = *(const short8*)(base + (y0*64 + x0 + 1)*128 + cg);
    short8 v10 = *(const short8*)(base + ((y0+1)*64 + x0    )*128 + cg);
    short8 v11 = *(const short8*)(base + ((y0+1)*64 + x0 + 1)*128 + cg);
    short8 outv;
    float sv = 0.f, s2 = 0.f;
    #pragma unroll
    for (int j = 0; j < 8; j++) {
        float val = w00*bf2f((unsigned short)v00[j]) + w01*bf2f((unsigned short)v01[j])
                  + w10*bf2f((unsigned short)v10[j]) + w11*bf2f((unsigned short)v11[j]);
        outv[j] = (short)f2bf(val);
        sv += val; s2 += val*val;
    }
    *(short8*)(XR + pix*128 + cg) = outv;
    #pragma unroll
    for (int d = 1; d < 16; d <<= 1) { sv += __shfl_xor(sv, d); s2 += __shfl_xor(s2, d); }
    if ((t & 15) == 0) {
        float m = sv * (1.0f/128.0f);
        float var = s2 * (1.0f/128.0f) - m*m;
        muR[pix] = m;
        rsR[pix] = rsqrtf(var + 1e-6f);
    }
}

// K3: NCHW f32 -> NHWC bf16 transpose of x_l + LN stats (float4 global loads).
__global__ void k_xl(const float* __restrict__ xl, unsigned short* __restrict__ XL,
                     float* __restrict__ muL, float* __restrict__ rsL)
{
    __shared__ float tile[128][33];
    __shared__ float partS[8][32];
    __shared__ float partS2[8][32];
    int blk = blockIdx.x;           // 4096 = 8 b * 512 chunks of 32 pixels
    int b  = blk >> 9;
    int p0 = (blk & 511) * 32;
    const float* src = xl + (long)b*128*16384;
    int t = threadIdx.x;            // 256
    #pragma unroll
    for (int k = 0; k < 4; k++) {
        int idx = t + 256*k;        // 1024 float4 groups
        int cc = idx >> 3, pi4 = (idx & 7) * 4;
        float4v v = *(const float4v*)&src[(long)cc*16384 + p0 + pi4];
        tile[cc][pi4+0] = v[0]; tile[cc][pi4+1] = v[1];
        tile[cc][pi4+2] = v[2]; tile[cc][pi4+3] = v[3];
    }
    __syncthreads();
    unsigned short* dst = XL + ((long)b*16384 + p0)*128;
    int cw = t & 127, ph = t >> 7;
    #pragma unroll
    for (int k = 0; k < 16; k++) {
        int pi = ph*16 + k;
        dst[(long)pi*128 + cw] = f2bf(tile[cw][pi]);
    }
    int sub = t >> 5, pj = t & 31;
    float sv = 0.f, s2 = 0.f;
    #pragma unroll
    for (int j = 0; j < 16; j++) { float v = tile[sub*16+j][pj]; sv += v; s2 += v*v; }
    partS[sub][pj] = sv; partS2[sub][pj] = s2;
    __syncthreads();
    if (t < 32) {
        float S = 0.f, S2 = 0.f;
        #pragma unroll
        for (int i = 0; i < 8; i++) { S += partS[i][t]; S2 += partS2[i][t]; }
        float m = S*(1.0f/128.0f), var = S2*(1.0f/128.0f) - m*m;
        muL[(long)b*16384 + p0 + t] = m;
        rsL[(long)b*16384 + p0 + t] = rsqrtf(var + 1e-6f);
    }
}

// K4: fused per-(b,h) SCAM. 8 waves x full row-blocks; LDS time-shared so
// footprint = 80384 B -> 2 workgroups/CU for cross-WG latency hiding.
#define LDQ 136
constexpr int K4_LDS = 2*128*LDQ*2 + (13*128 + 8*128)*4;   // 80384 B

__global__ __launch_bounds__(512, 4) void k_scam(
    const unsigned short* __restrict__ XL, const unsigned short* __restrict__ XR,
    const unsigned short* __restrict__ wl1e, const unsigned short* __restrict__ wr1e,
    const unsigned short* __restrict__ wl2b, const unsigned short* __restrict__ wr2b,
    const unsigned short* __restrict__ wf1b, const unsigned short* __restrict__ wf2b,
    const float* __restrict__ muL, const float* __restrict__ rsL,
    const float* __restrict__ muR, const float* __restrict__ rsR,
    const float* __restrict__ S1l, const float* __restrict__ S1r,
    const float* __restrict__ beffl, const float* __restrict__ beffr,
    const float* __restrict__ bl2, const float* __restrict__ br2,
    const float* __restrict__ beta, const float* __restrict__ gam,
    const float* __restrict__ bfv, float* __restrict__ out)
{
    extern __shared__ char smem[];
    unsigned short* bufA = (unsigned short*)smem;      // QLt -> P1 -> VL[c][w] -> A1t
    unsigned short* bufB = bufA + 128*LDQ;             // QRt -> P2t -> VR[c][v] -> A2t
    float* vecs = (float*)(bufB + 128*LDQ);            // 13 x 128
    float* colS = vecs + 13*128;                       // 8 x 128 col-sum partials

    int tid = threadIdx.x;
    int lane = tid & 63, wv = tid >> 6;    // 8 waves
    int l16 = lane & 15, lg = lane >> 4;
    int p0 = wv * 16;                       // this wave's 16 rows
    int bh = blockIdx.x;
    int b = bh >> 7, h = bh & 127;
    long pixbase = (long)b*16384 + (long)h*128;
    const unsigned short* Abl = XL + pixbase*128;
    const unsigned short* Abr = XR + pixbase*128;

    if (tid < 128) {
        vecs[0*128+tid]  = muL[pixbase + tid];
        vecs[1*128+tid]  = rsL[pixbase + tid];
        vecs[2*128+tid]  = muR[pixbase + tid];
        vecs[3*128+tid]  = rsR[pixbase + tid];
        vecs[4*128+tid]  = S1l[tid];
        vecs[5*128+tid]  = beffl[tid];
        vecs[6*128+tid]  = S1r[tid];
        vecs[7*128+tid]  = beffr[tid];
        vecs[8*128+tid]  = bl2[tid];
        vecs[9*128+tid]  = br2[tid];
        vecs[10*128+tid] = beta[tid];
        vecs[11*128+tid] = gam[tid];
        vecs[12*128+tid] = bfv[tid];
    }
    __syncthreads();                                   // B1

    f32x4 acc[8];
    auto conv = [&](const unsigned short* Asrc, const unsigned short* Wsrc){
        #pragma unroll
        for (int t = 0; t < 8; t++) acc[t] = (f32x4){0.f,0.f,0.f,0.f};
        #pragma unroll
        for (int kc = 0; kc < 4; kc++) {
            short8 a = *(const short8*)(Asrc + (p0+l16)*128 + kc*32 + lg*8);
            #pragma unroll
            for (int t = 0; t < 8; t++) {
                short8 bw = *(const short8*)(Wsrc + (t*16+l16)*128 + kc*32 + lg*8);
                acc[t] = MFMA16(a, bw, acc[t]);
            }
        }
    };
    auto epiQ = [&](const float* vmu, const float* vrs, const float* vS1,
                    const float* vbe, unsigned short* dstb){
        #pragma unroll
        for (int r = 0; r < 4; r++) {
            int p = p0 + lg*4 + r;
            float mu = vmu[p], rs = vrs[p];
            #pragma unroll
            for (int t = 0; t < 8; t++) {
                int o = t*16 + l16;
                dstb[p*LDQ + o] = f2bf(rs*(acc[t][r] - mu*vS1[o]) + vbe[o]);
            }
        }
    };

    // ----- Q convs ---------------------------------------------------------
    conv(Abl, wl1e); epiQ(vecs+0*128, vecs+1*128, vecs+4*128, vecs+5*128, bufA);
    conv(Abr, wr1e); epiQ(vecs+2*128, vecs+3*128, vecs+6*128, vecs+7*128, bufB);
    __syncthreads();                                   // B2

    // ----- S = QLt @ QRt^T (A: own rows of bufA; B: all rows of bufB) ------
    f32x4 s[8];
    #pragma unroll
    for (int t = 0; t < 8; t++) s[t] = (f32x4){0.f,0.f,0.f,0.f};
    #pragma unroll
    for (int kc = 0; kc < 4; kc++) {
        short8 a = *(const short8*)(bufA + (p0+l16)*LDQ + kc*32 + lg*8);
        #pragma unroll
        for (int t = 0; t < 8; t++) {
            short8 bq = *(const short8*)(bufB + (t*16+l16)*LDQ + kc*32 + lg*8);
            s[t] = MFMA16(a, bq, s[t]);
        }
    }
    // e = exp(S*scale)  (no max subtraction: |S*scale| small, f32-safe)
    const float scale = 0.08838834764831845f;   // 128^-0.5
    #pragma unroll
    for (int t = 0; t < 8; t++)
        #pragma unroll
        for (int r = 0; r < 4; r++) s[t][r] = __expf(s[t][r] * scale);

    // row sums (wave-local: full row in wave)
    float rsum[4];
    #pragma unroll
    for (int r = 0; r < 4; r++) {
        float a = 0.f;
        #pragma unroll
        for (int t = 0; t < 8; t++) a += s[t][r];
        #pragma unroll
        for (int d = 1; d < 16; d <<= 1) a += __shfl_xor(a, d);
        rsum[r] = a;
    }
    // col-sum partials (this wave's 16 rows)
    #pragma unroll
    for (int t = 0; t < 8; t++) {
        float a = s[t][0] + s[t][1] + s[t][2] + s[t][3];
        a += __shfl_xor(a, 16);
        a += __shfl_xor(a, 32);
        if (lane < 16) colS[wv*128 + t*16 + lane] = a;
    }
    __syncthreads();                                   // B3

    // P1 -> bufA (own rows, [w][v]); P2t -> bufB ([v][own w cols])
    #pragma unroll
    for (int r = 0; r < 4; r++) {
        float inv = 1.0f / rsum[r];
        #pragma unroll
        for (int t = 0; t < 8; t++)
            bufA[(p0 + lg*4 + r)*LDQ + t*16 + l16] = f2bf(s[t][r] * inv);
    }
    #pragma unroll
    for (int t = 0; t < 8; t++) {
        int col = t*16 + l16;
        float cs = 0.f;
        #pragma unroll
        for (int i = 0; i < 8; i++) cs += colS[i*128 + col];
        float inv = 1.0f / cs;
        #pragma unroll
        for (int r = 0; r < 4; r++)
            bufB[col*LDQ + p0 + lg*4 + r] = f2bf(s[t][r] * inv);
    }
    __syncthreads();                                   // B4

    // ----- preload P fragments to registers, then V-convs overwrite LDS ----
    short8 pa1[4], pa2[4];
    #pragma unroll
    for (int kc = 0; kc < 4; kc++) {
        pa1[kc] = *(const short8*)(bufA + (p0+l16)*LDQ + kc*32 + lg*8);  // P1[w][v]
        pa2[kc] = *(const short8*)(bufB + (p0+l16)*LDQ + kc*32 + lg*8);  // P2t[v][w]
    }
    conv(Abl, wl2b);                       // VL (global reads only, overlaps)
    __syncthreads();                                   // B5 (pa loads drained)
    {   // epiV: VL -> bufA as [c][w]
        #pragma unroll
        for (int t = 0; t < 8; t++) {
            int o = t*16 + l16;
            float bias = vecs[8*128 + o];
            #pragma unroll
            for (int r = 0; r < 4; r++)
                bufA[o*LDQ + p0 + lg*4 + r] = f2bf(acc[t][r] + bias);
        }
    }
    conv(Abr, wr2b);                       // VR
    {   // epiV: VR -> bufB as [c][v]
        #pragma unroll
        for (int t = 0; t < 8; t++) {
            int o = t*16 + l16;
            float bias = vecs[9*128 + o];
            #pragma unroll
            for (int r = 0; r < 4; r++)
                bufB[o*LDQ + p0 + lg*4 + r] = f2bf(acc[t][r] + bias);
        }
    }
    __syncthreads();                                   // B6

    // ----- PV GEMMs: A = P from regs, B = V from LDS -----------------------
    f32x4 f1[8], f2[8];
    #pragma unroll
    for (int t = 0; t < 8; t++) { f1[t] = (f32x4){0.f,0.f,0.f,0.f}; f2[t] = (f32x4){0.f,0.f,0.f,0.f}; }
    #pragma unroll
    for (int kc = 0; kc < 4; kc++) {
        #pragma unroll
        for (int t = 0; t < 8; t++) {
            short8 bv1 = *(const short8*)(bufB + (t*16+l16)*LDQ + kc*32 + lg*8); // VR[c][v]
            f1[t] = MFMA16(pa1[kc], bv1, f1[t]);
            short8 bv2 = *(const short8*)(bufA + (t*16+l16)*LDQ + kc*32 + lg*8); // VL[c][w]
            f2[t] = MFMA16(pa2[kc], bv2, f2[t]);
        }
    }
    __syncthreads();                                   // B7

    // ----- residual + beta/gamma -> A1t/A2t [p][c] -------------------------
    #pragma unroll
    for (int t = 0; t < 8; t++) {
        int c = t*16 + l16;
        float bet = vecs[10*128 + c], gm = vecs[11*128 + c];
        #pragma unroll
        for (int r = 0; r < 4; r++) {
            int p = p0 + lg*4 + r;
            float xlv = bf2f(Abl[p*128 + c]);
            bufA[p*LDQ + c] = f2bf(xlv + bet*f1[t][r]);
            float xrv = bf2f(Abr[p*128 + c]);
            bufB[p*LDQ + c] = f2bf(xrv + gm*f2[t][r]);
        }
    }
    __syncthreads();                                   // B8

    // ----- final conv: out[o][w] = Wf1@A1t + Wf2@A2t + bf ------------------
    f32x4 oacc[8];
    #pragma unroll
    for (int t = 0; t < 8; t++) oacc[t] = (f32x4){0.f,0.f,0.f,0.f};
    #pragma unroll
    for (int kc = 0; kc < 4; kc++) {
        short8 aw1 = *(const short8*)(wf1b + (p0+l16)*128 + kc*32 + lg*8);
        short8 aw2 = *(const short8*)(wf2b + (p0+l16)*128 + kc*32 + lg*8);
        #pragma unroll
        for (int t = 0; t < 8; t++) {
            short8 b1 = *(const short8*)(bufA + (t*16+l16)*LDQ + kc*32 + lg*8);
            oacc[t] = MFMA16(aw1, b1, oacc[t]);
            short8 b2 = *(const short8*)(bufB + (t*16+l16)*LDQ + kc*32 + lg*8);
            oacc[t] = MFMA16(aw2, b2, oacc[t]);
        }
    }
    float* outb = out + (long)b*2097152 + (long)h*128;
    #pragma unroll
    for (int t = 0; t < 8; t++) {
        #pragma unroll
        for (int r = 0; r < 4; r++) {
            int o = p0 + lg*4 + r;
            outb[(long)o*16384 + t*16 + l16] = oacc[t][r] + vecs[12*128 + o];
        }
    }
}

// ---------------------------------------------------------------------------
extern "C" void kernel_launch(void* const* d_in, const int* in_sizes, int n_in,
                              void* d_out, int out_size, void* d_ws, size_t ws_size,
                              hipStream_t stream)
{
    const float* x_l = (const float*)d_in[0];
    const float* x_r = (const float*)d_in[1];
    const float* Wm  = (const float*)d_in[2];
    const float* bm  = (const float*)d_in[3];
    const float* nlw = (const float*)d_in[4];
    const float* nlb = (const float*)d_in[5];
    const float* nrw = (const float*)d_in[6];
    const float* nrb = (const float*)d_in[7];
    const float* Wl1 = (const float*)d_in[8];
    const float* bl1 = (const float*)d_in[9];
    const float* Wr1 = (const float*)d_in[10];
    const float* br1 = (const float*)d_in[11];
    const float* Wl2 = (const float*)d_in[12];
    const float* bl2 = (const float*)d_in[13];
    const float* Wr2 = (const float*)d_in[14];
    const float* br2 = (const float*)d_in[15];
    const float* beta = (const float*)d_in[16];
    const float* gam  = (const float*)d_in[17];
    const float* Wf   = (const float*)d_in[18];
    const float* bf   = (const float*)d_in[19];
    float* out = (float*)d_out;

    char* ws = (char*)d_ws;
    size_t off = 0;
    auto alloc = [&](size_t bytes) -> void* {
        void* p = ws + off;
        off += (bytes + 255) & ~(size_t)255;
        return p;
    };
    unsigned short* XL   = (unsigned short*)alloc((size_t)16777216*2);
    unsigned short* XR   = (unsigned short*)alloc((size_t)16777216*2);
    unsigned short* R0n  = (unsigned short*)alloc((size_t)4194304*2);
    float* muL = (float*)alloc((size_t)131072*4);
    float* rsL = (float*)alloc((size_t)131072*4);
    float* muR = (float*)alloc((size_t)131072*4);
    float* rsR = (float*)alloc((size_t)131072*4);
    unsigned short* wl1e = (unsigned short*)alloc((size_t)16384*2);
    unsigned short* wr1e = (unsigned short*)alloc((size_t)16384*2);
    unsigned short* wl2b = (unsigned short*)alloc((size_t)16384*2);
    unsigned short* wr2b = (unsigned short*)alloc((size_t)16384*2);
    unsigned short* wf1b = (unsigned short*)alloc((size_t)16384*2);
    unsigned short* wf2b = (unsigned short*)alloc((size_t)16384*2);
    float* S1l   = (float*)alloc(128*4);
    float* S1r   = (float*)alloc(128*4);
    float* beffl = (float*)alloc(128*4);
    float* beffr = (float*)alloc(128*4);

    (void)in_sizes; (void)n_in; (void)out_size; (void)ws_size;

    hipFuncSetAttribute((const void*)k_scam,
                        hipFuncAttributeMaxDynamicSharedMemorySize, K4_LDS);

    k_prep<<<128, 128, 0, stream>>>(Wl1, bl1, Wr1, br1, Wl2, Wr2, Wf,
                                    nlw, nlb, nrw, nrb,
                                    wl1e, wr1e, wl2b, wr2b, wf1b, wf2b,
                                    S1l, S1r, beffl, beffr);
    k_memconv<<<512, 256, 0, stream>>>(x_r, Wm, bm, R0n);
    k_xr<<<8192, 256, 0, stream>>>(R0n, XR, muR, rsR);
    k_xl<<<4096, 256, 0, stream>>>(x_l, XL, muL, rsL);
    k_scam<<<1024, 512, K4_LDS, stream>>>(XL, XR, wl1e, wr1e, wl2b, wr2b,
                                          wf1b, wf2b, muL, rsL, muR, rsR,
                                          S1l, S1r, beffl, beffr,
                                          bl2, br2, beta, gam, bf, out);
}